// Round 14
// baseline (155.078 us; speedup 1.0000x reference)
//
#include <hip/hip_runtime.h>
#include <stdint.h>

typedef unsigned short u16;
typedef __bf16 bf16_t;
typedef bf16_t v8bf __attribute__((ext_vector_type(8)));
typedef float v4f __attribute__((ext_vector_type(4)));

#define SEQ   4096
#define HIDN  1024
#define NHEAD 16
#define HDIM  64
#define BLK   256
#define NBLK  16

#define GLOAD_LDS16(g, l) __builtin_amdgcn_global_load_lds( \
  (const __attribute__((address_space(1))) unsigned*)(g), \
  (__attribute__((address_space(3))) unsigned*)(l), 16, 0, 0)

__device__ __forceinline__ u16 f2bf(float f){
  union { __bf16 b; u16 u; } v; v.b = (__bf16)f;   // 1 inst, RNE
  return v.u;
}
__device__ __forceinline__ float bf2f(u16 h){
  union { unsigned u; float f; } v; v.u = ((unsigned)h) << 16;
  return v.f;
}
__device__ __forceinline__ unsigned packbf(float a, float b){
  unsigned r;
  asm("v_cvt_pk_bf16_f32 %0, %1, %2" : "=v"(r) : "v"(a), "v"(b));
  return r;
}

// ---------------- fused prep: W transposes + hidden convert + bcat + pos_proj ----------------
__global__ __launch_bounds__(256) void k_prep(const float* __restrict__ hidden, u16* __restrict__ hb,
    const float* __restrict__ Wq, const float* __restrict__ Wk,
    const float* __restrict__ Wv, const float* __restrict__ Wo, u16* __restrict__ Wt,
    const float* __restrict__ bq, const float* __restrict__ bk, const float* __restrict__ bv,
    float* __restrict__ bcat,
    const float* __restrict__ rpe, float* __restrict__ posk, float* __restrict__ posq0)
{
  __shared__ float t[32][33];
  __shared__ float red[4][64];
  int b = blockIdx.x, tid = threadIdx.x;
  if (b < 4096){
    int w = b >> 10, tile = b & 1023;
    int k0 = (tile & 31) * 32, n0 = (tile >> 5) * 32;
    const float* W = (w == 0) ? Wq : (w == 1) ? Wk : (w == 2) ? Wv : Wo;
    u16* outp = Wt + (size_t)w * 1024 * 1024;
    int x = tid & 31, y = tid >> 5;
    #pragma unroll
    for (int yy = 0; yy < 32; yy += 8) t[y + yy][x] = W[(size_t)(k0 + y + yy) * 1024 + n0 + x];
    __syncthreads();
    #pragma unroll
    for (int yy = 0; yy < 32; yy += 8) outp[(size_t)(n0 + y + yy) * 1024 + k0 + x] = f2bf(t[x][y + yy]);
  } else if (b < 4608){
    int base = (b - 4096) * 8192;
    #pragma unroll
    for (int j = 0; j < 8; j++){
      int i = base + j * 1024 + tid * 4;
      float4 f = *(const float4*)&hidden[i];
      uint2 p; p.x = packbf(f.x, f.y); p.y = packbf(f.z, f.w);
      *(uint2*)&hb[i] = p;
    }
  } else if (b == 4608){
    #pragma unroll
    for (int j = 0; j < 12; j++){
      int i = j * 256 + tid;
      const float* src = i < 1024 ? bq : (i < 2048 ? bk : bv);
      bcat[i] = src[i & 1023];
    }
  } else {
    int pb = b - 4609;   // [0,257)
    int d = tid & 63, part = tid >> 6;
    const float* W  = (pb < 256) ? Wk : Wq;
    const float* rv = (pb < 256) ? &rpe[(size_t)pb * 1024] : rpe;
    float s = 0.f;
    for (int k = part * 256; k < part * 256 + 256; k++) s += rv[k] * W[(size_t)k * 1024 + d];
    red[part][d] = s;
    __syncthreads();
    if (part == 0){
      s = red[0][d] + red[1][d] + red[2][d] + red[3][d];
      if (pb < 256) posk[pb * 64 + d] = s + bk[d];
      else          posq0[d] = s + bq[d];
    }
  }
}

// ---------------- QKV GEMM, 2-phase dbuf pipeline: qk[S][2048] = Q|K ; Vt[c][s] for V ----------------
__global__ __launch_bounds__(256) void k_gemm_qkv(const u16* __restrict__ A, const u16* __restrict__ Bt,
                                                  const float* __restrict__ bias,
                                                  u16* __restrict__ qk, u16* __restrict__ Vt)
{
  __shared__ alignas(16) u16 As[2][128 * 32];
  __shared__ alignas(16) u16 Bs[2][128 * 32];
  int tid = threadIdx.x, lane = tid & 63, wid = tid >> 6;
  int wr = wid >> 1, wc = wid & 1;
  int m0 = blockIdx.y * 128, n0 = blockIdx.x * 128;
  const int K = 1024;

  v4f acc[4][4];
  #pragma unroll
  for (int m = 0; m < 4; m++)
    #pragma unroll
    for (int n = 0; n < 4; n++) acc[m][n] = (v4f){0.f, 0.f, 0.f, 0.f};

  int r = lane & 15, g = lane >> 4;
  int ob0 = wid * 2048;
  int o0  = ob0 + lane * 16;
  int row0 = o0 >> 6, col0 = (o0 & 63) >> 1;
  int row1 = (o0 + 1024) >> 6, col1 = ((o0 + 1024) & 63) >> 1;

  GLOAD_LDS16(&A [(size_t)(m0 + row0) * K + col0], &As[0][ob0 >> 1]);
  GLOAD_LDS16(&Bt[(size_t)(n0 + row0) * K + col0], &Bs[0][ob0 >> 1]);
  GLOAD_LDS16(&A [(size_t)(m0 + row1) * K + col1], &As[0][(ob0 + 1024) >> 1]);
  GLOAD_LDS16(&Bt[(size_t)(n0 + row1) * K + col1], &Bs[0][(ob0 + 1024) >> 1]);
  __syncthreads();

  int cur = 0;
  for (int kt = 0; kt < K - 32; kt += 32){
    int nx = cur ^ 1, kn = kt + 32;
    GLOAD_LDS16(&A [(size_t)(m0 + row0) * K + kn + col0], &As[nx][ob0 >> 1]);
    GLOAD_LDS16(&Bt[(size_t)(n0 + row0) * K + kn + col0], &Bs[nx][ob0 >> 1]);
    GLOAD_LDS16(&A [(size_t)(m0 + row1) * K + kn + col1], &As[nx][(ob0 + 1024) >> 1]);
    GLOAD_LDS16(&Bt[(size_t)(n0 + row1) * K + kn + col1], &Bs[nx][(ob0 + 1024) >> 1]);

    v8bf a[4], bb[4];
    #pragma unroll
    for (int m = 0; m < 4; m++) a[m] = *(const v8bf*)&As[cur][(wr * 64 + m * 16 + r) * 32 + g * 8];
    #pragma unroll
    for (int n = 0; n < 4; n++) bb[n] = *(const v8bf*)&Bs[cur][(wc * 64 + n * 16 + r) * 32 + g * 8];
    #pragma unroll
    for (int m = 0; m < 4; m++)
      #pragma unroll
      for (int n = 0; n < 4; n++)
        acc[m][n] = __builtin_amdgcn_mfma_f32_16x16x32_bf16(a[m], bb[n], acc[m][n], 0, 0, 0);
    __syncthreads();
    cur = nx;
  }
  {
    v8bf a[4], bb[4];
    #pragma unroll
    for (int m = 0; m < 4; m++) a[m] = *(const v8bf*)&As[cur][(wr * 64 + m * 16 + r) * 32 + g * 8];
    #pragma unroll
    for (int n = 0; n < 4; n++) bb[n] = *(const v8bf*)&Bs[cur][(wc * 64 + n * 16 + r) * 32 + g * 8];
    #pragma unroll
    for (int m = 0; m < 4; m++)
      #pragma unroll
      for (int n = 0; n < 4; n++)
        acc[m][n] = __builtin_amdgcn_mfma_f32_16x16x32_bf16(a[m], bb[n], acc[m][n], 0, 0, 0);
  }

  #pragma unroll
  for (int m = 0; m < 4; m++)
    #pragma unroll
    for (int n = 0; n < 4; n++){
      int col = n0 + wc * 64 + n * 16 + r;
      float bv = bias[col];
      if (n0 < 2048){
        #pragma unroll
        for (int i = 0; i < 4; i++){
          int row = m0 + wr * 64 + m * 16 + g * 4 + i;
          qk[(size_t)row * 2048 + col] = f2bf(acc[m][n][i] + bv);
        }
      } else {
        uint2 pk;
        pk.x = packbf(acc[m][n][0] + bv, acc[m][n][1] + bv);
        pk.y = packbf(acc[m][n][2] + bv, acc[m][n][3] + bv);
        int row = m0 + wr * 64 + m * 16 + g * 4;
        *(uint2*)&Vt[(size_t)(col - 2048) * 4096 + row] = pk;
      }
    }
}

// ---------------- out GEMM + residual, same 2-phase dbuf ----------------
__global__ __launch_bounds__(256) void k_gemm_out(const u16* __restrict__ A, const u16* __restrict__ Bt,
                                                  const float* __restrict__ bias,
                                                  const float* __restrict__ resid, float* __restrict__ Cout)
{
  __shared__ alignas(16) u16 As[2][128 * 32];
  __shared__ alignas(16) u16 Bs[2][128 * 32];
  int tid = threadIdx.x, lane = tid & 63, wid = tid >> 6;
  int wr = wid >> 1, wc = wid & 1;
  int m0 = blockIdx.y * 128, n0 = blockIdx.x * 128;
  const int K = 1024;

  v4f acc[4][4];
  #pragma unroll
  for (int m = 0; m < 4; m++)
    #pragma unroll
    for (int n = 0; n < 4; n++) acc[m][n] = (v4f){0.f, 0.f, 0.f, 0.f};

  int r = lane & 15, g = lane >> 4;
  int ob0 = wid * 2048;
  int o0  = ob0 + lane * 16;
  int row0 = o0 >> 6, col0 = (o0 & 63) >> 1;
  int row1 = (o0 + 1024) >> 6, col1 = ((o0 + 1024) & 63) >> 1;

  GLOAD_LDS16(&A [(size_t)(m0 + row0) * K + col0], &As[0][ob0 >> 1]);
  GLOAD_LDS16(&Bt[(size_t)(n0 + row0) * K + col0], &Bs[0][ob0 >> 1]);
  GLOAD_LDS16(&A [(size_t)(m0 + row1) * K + col1], &As[0][(ob0 + 1024) >> 1]);
  GLOAD_LDS16(&Bt[(size_t)(n0 + row1) * K + col1], &Bs[0][(ob0 + 1024) >> 1]);
  __syncthreads();

  int cur = 0;
  for (int kt = 0; kt < K - 32; kt += 32){
    int nx = cur ^ 1, kn = kt + 32;
    GLOAD_LDS16(&A [(size_t)(m0 + row0) * K + kn + col0], &As[nx][ob0 >> 1]);
    GLOAD_LDS16(&Bt[(size_t)(n0 + row0) * K + kn + col0], &Bs[nx][ob0 >> 1]);
    GLOAD_LDS16(&A [(size_t)(m0 + row1) * K + kn + col1], &As[nx][(ob0 + 1024) >> 1]);
    GLOAD_LDS16(&Bt[(size_t)(n0 + row1) * K + kn + col1], &Bs[nx][(ob0 + 1024) >> 1]);

    v8bf a[4], bb[4];
    #pragma unroll
    for (int m = 0; m < 4; m++) a[m] = *(const v8bf*)&As[cur][(wr * 64 + m * 16 + r) * 32 + g * 8];
    #pragma unroll
    for (int n = 0; n < 4; n++) bb[n] = *(const v8bf*)&Bs[cur][(wc * 64 + n * 16 + r) * 32 + g * 8];
    #pragma unroll
    for (int m = 0; m < 4; m++)
      #pragma unroll
      for (int n = 0; n < 4; n++)
        acc[m][n] = __builtin_amdgcn_mfma_f32_16x16x32_bf16(a[m], bb[n], acc[m][n], 0, 0, 0);
    __syncthreads();
    cur = nx;
  }
  {
    v8bf a[4], bb[4];
    #pragma unroll
    for (int m = 0; m < 4; m++) a[m] = *(const v8bf*)&As[cur][(wr * 64 + m * 16 + r) * 32 + g * 8];
    #pragma unroll
    for (int n = 0; n < 4; n++) bb[n] = *(const v8bf*)&Bs[cur][(wc * 64 + n * 16 + r) * 32 + g * 8];
    #pragma unroll
    for (int m = 0; m < 4; m++)
      #pragma unroll
      for (int n = 0; n < 4; n++)
        acc[m][n] = __builtin_amdgcn_mfma_f32_16x16x32_bf16(a[m], bb[n], acc[m][n], 0, 0, 0);
  }

  #pragma unroll
  for (int m = 0; m < 4; m++)
    #pragma unroll
    for (int n = 0; n < 4; n++){
      int col = n0 + wc * 64 + n * 16 + r;
      float bv = bias[col];
      #pragma unroll
      for (int i = 0; i < 4; i++){
        int row = m0 + wr * 64 + m * 16 + g * 4 + i;
        Cout[(size_t)row * 1024 + col] = acc[m][n][i] + bv + resid[(size_t)row * 1024 + col];
      }
    }
}

// ---------------- brow: 8 WGs, 32 rows each; also zeros brow[0,256) ----------------
__global__ __launch_bounds__(256) void k_brow(const u16* __restrict__ qk,
                                              const float* __restrict__ posk, const float* __restrict__ posq0,
                                              float* __restrict__ brow)
{
  int b = blockIdx.x, tid = threadIdx.x;
  if (tid < 32) brow[b * 32 + tid] = 0.f;
  int u = b * 32 + (tid >> 3), sub = tid & 7;
  float c2p = 0.f, p2c = 0.f;
  #pragma unroll
  for (int j = 0; j < 8; j++){
    int d = sub * 8 + j;
    c2p += bf2f(qk[d]) * posk[u * 64 + d];
    p2c += posq0[d] * bf2f(qk[(size_t)u * 2048 + 1024 + d]);
  }
  float v = c2p + p2c;
  v += __shfl_xor(v, 1);
  v += __shfl_xor(v, 2);
  v += __shfl_xor(v, 4);
  if (sub == 0) brow[256 + u] = v;
}

// ---------------- biasd[t] = brow[clip(bucket(t-767)+256)] * c1 (prescaled) ----------------
__global__ void k_biasd(const float* __restrict__ brow, float* __restrict__ biasd)
{
  const float c1 = 0.07216878364870323f * 1.4426950408889634f;  // 1/sqrt(192)*log2e
  int t = blockIdx.x * blockDim.x + threadIdx.x;   // 1024
  int rel = t - 767;
  int bucket;
  bool in_exact = (rel < 128) && (rel > -128);
  int abs_pos = in_exact ? 127 : (rel < 0 ? -rel : rel);
  if (abs_pos <= 128) bucket = rel;
  else {
    float xx = logf((float)abs_pos * (1.0f / 128.0f)) / logf(255.0f / 128.0f);
    float lp = ceilf(xx * 127.0f) + 128.0f;
    int sgn = (rel > 0) ? 1 : ((rel < 0) ? -1 : 0);
    bucket = (int)lp * sgn;
  }
  int idx = bucket + 256;
  idx = idx < 0 ? 0 : (idx > 511 ? 511 : idx);
  biasd[t] = brow[idx] * c1;
}

// ---------------- flash attention, swapped QK^T, in-register P (R12 structure) ----------------
// Grid head-major: consecutive blocks = adjacent q-tiles of the SAME head -> K/V L2 reuse.
__global__ __launch_bounds__(256) void k_attn(const u16* __restrict__ qk, const u16* __restrict__ Vt,
                                              const float* __restrict__ biasd, u16* __restrict__ ctxg)
{
  __shared__ alignas(16) u16 Ks[128 * 64];     // 16KB, slot-swizzled rows
  __shared__ alignas(16) u16 Vs[64 * 128];     // 16KB, slot-swizzled rows (d-major)
  __shared__ float bias_s[1024];               // prescaled by c1

  int b = blockIdx.x;
  int tile = b & 63, h = b >> 6;               // head-major ordering
  int n = tile >> 2, qb0 = (tile & 3) * 64;
  int tid = threadIdx.x, lane = tid & 63, w = tid >> 6;
  int q0 = tile * 64;
  int g0 = (n - 1) * 256;
  const float c1 = 0.07216878364870323f * 1.4426950408889634f;  // 1/sqrt(192)*log2e
  int r = lane & 15, g = lane >> 4;

  *(float4*)&bias_s[tid * 4] = *(const float4*)&biasd[tid * 4];

  // Q fragments (B-operand): lane holds Q[q0+w*16+r][ks*32 + g*8 + j]
  v8bf qfrag[2];
  {
    const u16* src = &qk[(size_t)(q0 + w * 16 + r) * 2048 + h * 64 + g * 8];
    qfrag[0] = *(const v8bf*)&src[0];
    qfrag[1] = *(const v8bf*)&src[32];
  }

  float mrun = -3.0e38f, lrun = 0.f;
  v4f pacc[4];                                  // O[q=g*4+i][d=nn*16+r]
  #pragma unroll
  for (int nn = 0; nn < 4; nn++) pacc[nn] = (v4f){0.f,0.f,0.f,0.f};

  int idxA = r + ((g & 1) << 5);                // exchange sources
  int idxB = idxA + 16;
  int myrnd = g >> 1;

  for (int c = 0; c < 6; ++c){
    int cb = g0 + c * 128;
    bool oob = (cb < 0) || (cb >= SEQ);
    if (!oob){
      #pragma unroll
      for (int t = 0; t < 4; ++t){       // K rows w*32 + t*8 + (lane>>3)
        int row = w * 32 + t * 8 + (lane >> 3);
        int p = lane & 7;
        GLOAD_LDS16(&qk[(size_t)(cb + row) * 2048 + 1024 + h * 64 + ((p ^ (row & 7)) * 8)],
                    Ks + (size_t)(w * 32 + t * 8) * 64);
      }
      #pragma unroll
      for (int t = 0; t < 4; ++t){       // V d-rows w*16 + t*4 + (lane>>4)
        int d = w * 16 + t * 4 + (lane >> 4);
        int p = lane & 15;
        GLOAD_LDS16(&Vt[(size_t)(h * 64 + d) * 4096 + cb + ((p ^ (d & 7)) * 8)],
                    Vs + (size_t)(w * 16 + t * 4) * 128);
      }
    }
    __syncthreads();

    // swapped QK: sacc[t] = P fragment, rows k = t*16 + g*4 + i, col q = r
    v4f sacc[8];
    #pragma unroll
    for (int t = 0; t < 8; t++) sacc[t] = (v4f){0.f,0.f,0.f,0.f};
    if (!oob){
      __builtin_amdgcn_s_setprio(1);
      #pragma unroll
      for (int ks = 0; ks < 2; ++ks){
        #pragma unroll
        for (int t = 0; t < 8; t++){
          int kr = t * 16 + r;
          v8bf kf = *(const v8bf*)&Ks[kr * 64 + (((4 * ks + g) ^ (kr & 7)) * 8)];
          sacc[t] = __builtin_amdgcn_mfma_f32_16x16x32_bf16(kf, qfrag[ks], sacc[t], 0, 0, 0);
        }
      }
      __builtin_amdgcn_s_setprio(0);
    }

    // scores (prescaled bias -> single fma) + in-lane chunk max
    float sv[8][4];
    float cmax = -3.0e38f;
    int ib = qb0 + w * 16 + r + 767 - c * 128 - g * 4;
    #pragma unroll
    for (int t = 0; t < 8; t++){
      #pragma unroll
      for (int i = 0; i < 4; i++)
        sv[t][i] = fmaf(sacc[t][i], c1, bias_s[ib - t * 16 - i]);
      float m01 = fmaxf(sv[t][0], sv[t][1]);
      float m23 = fmaxf(sv[t][2], sv[t][3]);
      cmax = fmaxf(cmax, fmaxf(m01, m23));
    }
    cmax = fmaxf(cmax, __shfl_xor(cmax, 16));
    cmax = fmaxf(cmax, __shfl_xor(cmax, 32));
    // defer-max: only rescale when the chunk max meaningfully exceeds the running max
    if (!__all(cmax <= mrun + 8.f)){
      float mn = fmaxf(mrun, cmax);
      float sc = exp2f(mrun - mn);
      mrun = mn;
      lrun *= sc;
      #pragma unroll
      for (int i = 0; i < 4; i++){
        float sci = __shfl(sc, (g << 2) + i);
        #pragma unroll
        for (int nn = 0; nn < 4; nn++) pacc[nn][i] *= sci;
      }
    }

    // exp + bf16 pack via v_cvt_pk_bf16_f32
    unsigned pk0[8], pk1[8];
    #pragma unroll
    for (int t = 0; t < 8; t++){
      float p0 = exp2f(sv[t][0] - mrun);
      float p1 = exp2f(sv[t][1] - mrun);
      float p2 = exp2f(sv[t][2] - mrun);
      float p3 = exp2f(sv[t][3] - mrun);
      lrun += (p0 + p1) + (p2 + p3);
      pk0[t] = packbf(p0, p1);
      pk1[t] = packbf(p2, p3);
    }

    // exchange + PV: A-frag for ks block bb4 = P[q=r][k = bb4*32 + g*8 + j]
    if (!oob){
      #pragma unroll
      for (int bb4 = 0; bb4 < 4; ++bb4){
        unsigned s0a = 0, s1a = 0, s0b = 0, s1b = 0;
        #pragma unroll
        for (int rnd = 0; rnd < 2; ++rnd){
          int t = 2 * bb4 + rnd;
          unsigned ta0 = __shfl(pk0[t], idxA);
          unsigned ta1 = __shfl(pk1[t], idxA);
          unsigned tb0 = __shfl(pk0[t], idxB);
          unsigned tb1 = __shfl(pk1[t], idxB);
          if (myrnd == rnd){ s0a = ta0; s1a = ta1; s0b = tb0; s1b = tb1; }
        }
        union { unsigned u[4]; v8bf v; } af;
        af.u[0] = s0a; af.u[1] = s1a; af.u[2] = s0b; af.u[3] = s1b;
        __builtin_amdgcn_s_setprio(1);
        #pragma unroll
        for (int nn = 0; nn < 4; nn++){
          int d = nn * 16 + r;
          v8bf vb = *(const v8bf*)&Vs[d * 128 + (((4 * bb4 + g) ^ (d & 7)) * 8)];
          pacc[nn] = __builtin_amdgcn_mfma_f32_16x16x32_bf16(af.v, vb, pacc[nn], 0, 0, 0);
        }
        __builtin_amdgcn_s_setprio(0);
      }
    }
    __syncthreads();   // protect Ks/Vs for next chunk
  }

  // final: l for q=r across g-groups, broadcast inverse to output-row owners
  lrun += __shfl_xor(lrun, 16);
  lrun += __shfl_xor(lrun, 32);
  float inv = 1.0f / lrun;
  #pragma unroll
  for (int nn = 0; nn < 4; nn++){
    int d = nn * 16 + r;
    #pragma unroll
    for (int i = 0; i < 4; i++){
      float invi = __shfl(inv, (g << 2) + i);
      int qrow = q0 + w * 16 + g * 4 + i;
      ctxg[(size_t)qrow * 1024 + h * 64 + d] = f2bf(pacc[nn][i] * invi);
    }
  }
}

// ---------------- LayerNorm in place (residual already folded into out) ----------------
__global__ __launch_bounds__(256) void k_ln(float* __restrict__ out,
                                            const float* __restrict__ gamma, const float* __restrict__ beta)
{
  __shared__ float red[8];
  int row = blockIdx.x, tid = threadIdx.x;
  int lane = tid & 63, wid = tid >> 6;
  size_t base = (size_t)row * 1024 + tid * 4;
  float4 xv = *(const float4*)&out[base];
  float v0 = xv.x, v1 = xv.y, v2 = xv.z, v3 = xv.w;
  float s = v0 + v1 + v2 + v3;
  float q = v0 * v0 + v1 * v1 + v2 * v2 + v3 * v3;
  #pragma unroll
  for (int o = 32; o; o >>= 1){ s += __shfl_down(s, o); q += __shfl_down(q, o); }
  if (lane == 0){ red[wid] = s; red[4 + wid] = q; }
  __syncthreads();
  float ts = red[0] + red[1] + red[2] + red[3];
  float tq = red[4] + red[5] + red[6] + red[7];
  float mu = ts * (1.0f / 1024.0f);
  float var = tq * (1.0f / 1024.0f) - mu * mu;
  float rstd = rsqrtf(var + 1e-7f);
  int c = tid * 4;
  out[base + 0] = (v0 - mu) * rstd * gamma[c + 0] + beta[c + 0];
  out[base + 1] = (v1 - mu) * rstd * gamma[c + 1] + beta[c + 1];
  out[base + 2] = (v2 - mu) * rstd * gamma[c + 2] + beta[c + 2];
  out[base + 3] = (v3 - mu) * rstd * gamma[c + 3] + beta[c + 3];
}

extern "C" void kernel_launch(void* const* d_in, const int* in_sizes, int n_in,
                              void* d_out, int out_size, void* d_ws, size_t ws_size,
                              hipStream_t stream)
{
  const float* hidden = (const float*)d_in[0];
  const float* rpe    = (const float*)d_in[1];
  const float* Wq = (const float*)d_in[2];
  const float* bq = (const float*)d_in[3];
  const float* Wk = (const float*)d_in[4];
  const float* bk = (const float*)d_in[5];
  const float* Wv = (const float*)d_in[6];
  const float* bv = (const float*)d_in[7];
  const float* Wo = (const float*)d_in[8];
  const float* bo = (const float*)d_in[9];
  const float* lns = (const float*)d_in[10];
  const float* lnb = (const float*)d_in[11];
  float* out = (float*)d_out;

  char* ws = (char*)d_ws;
  size_t off = 0;
  auto alloc = [&](size_t bytes){ void* p = ws + off; off += (bytes + 255) & ~(size_t)255; return p; };
  u16* hb      = (u16*)alloc((size_t)SEQ * HIDN * 2);
  u16* Wt      = (u16*)alloc((size_t)4 * HIDN * HIDN * 2);    // [Wqt|Wkt|Wvt|Wot]
  u16* qk      = (u16*)alloc((size_t)SEQ * 2048 * 2);
  u16* Vt      = (u16*)alloc((size_t)HIDN * SEQ * 2);
  u16* ctxb    = (u16*)alloc((size_t)SEQ * HIDN * 2);
  float* bcat  = (float*)alloc(3072 * 4);
  float* poskf = (float*)alloc(256 * 64 * 4);
  float* posq0 = (float*)alloc(64 * 4);
  float* brow  = (float*)alloc(512 * 4);
  float* biasd = (float*)alloc(1024 * 4);
  (void)ws_size; (void)in_sizes; (void)n_in; (void)out_size;

  k_prep<<<4866, 256, 0, stream>>>(hidden, hb, Wq, Wk, Wv, Wo, Wt,
                                   bq, bk, bv, bcat, rpe, poskf, posq0);

  k_gemm_qkv<<<dim3(24, 32), 256, 0, stream>>>(hb, Wt, bcat, qk, Vt);

  k_brow<<<8, 256, 0, stream>>>(qk, poskf, posq0, brow);
  k_biasd<<<4, 256, 0, stream>>>(brow, biasd);

  k_attn<<<64 * NHEAD, 256, 0, stream>>>(qk, Vt, biasd, ctxb);

  k_gemm_out<<<dim3(8, 32), 256, 0, stream>>>(ctxb, Wt + (size_t)3 * HIDN * HIDN, bo, hidden, out);

  k_ln<<<SEQ, 256, 0, stream>>>(out, lns, lnb);
}

// Round 15
// 143.164 us; speedup vs baseline: 1.0832x; 1.0832x over previous
//
#include <hip/hip_runtime.h>
#include <stdint.h>

typedef unsigned short u16;
typedef __bf16 bf16_t;
typedef bf16_t v8bf __attribute__((ext_vector_type(8)));
typedef float v4f __attribute__((ext_vector_type(4)));

#define SEQ   4096
#define HIDN  1024
#define NHEAD 16
#define HDIM  64
#define BLK   256
#define NBLK  16

#define GLOAD_LDS16(g, l) __builtin_amdgcn_global_load_lds( \
  (const __attribute__((address_space(1))) unsigned*)(g), \
  (__attribute__((address_space(3))) unsigned*)(l), 16, 0, 0)

__device__ __forceinline__ u16 f2bf(float f){
  union { __bf16 b; u16 u; } v; v.b = (__bf16)f;   // 1 inst, RNE
  return v.u;
}
__device__ __forceinline__ float bf2f(u16 h){
  union { unsigned u; float f; } v; v.u = ((unsigned)h) << 16;
  return v.f;
}
__device__ __forceinline__ unsigned packbf(float a, float b){
  unsigned r;
  asm("v_cvt_pk_bf16_f32 %0, %1, %2" : "=v"(r) : "v"(a), "v"(b));
  return r;
}

// ---------------- fused prep: W transposes + hidden convert + bcat + pos_proj ----------------
__global__ __launch_bounds__(256) void k_prep(const float* __restrict__ hidden, u16* __restrict__ hb,
    const float* __restrict__ Wq, const float* __restrict__ Wk,
    const float* __restrict__ Wv, const float* __restrict__ Wo, u16* __restrict__ Wt,
    const float* __restrict__ bq, const float* __restrict__ bk, const float* __restrict__ bv,
    float* __restrict__ bcat,
    const float* __restrict__ rpe, float* __restrict__ posk, float* __restrict__ posq0)
{
  __shared__ float t[32][33];
  __shared__ float red[4][64];
  int b = blockIdx.x, tid = threadIdx.x;
  if (b < 4096){
    int w = b >> 10, tile = b & 1023;
    int k0 = (tile & 31) * 32, n0 = (tile >> 5) * 32;
    const float* W = (w == 0) ? Wq : (w == 1) ? Wk : (w == 2) ? Wv : Wo;
    u16* outp = Wt + (size_t)w * 1024 * 1024;
    int x = tid & 31, y = tid >> 5;
    #pragma unroll
    for (int yy = 0; yy < 32; yy += 8) t[y + yy][x] = W[(size_t)(k0 + y + yy) * 1024 + n0 + x];
    __syncthreads();
    #pragma unroll
    for (int yy = 0; yy < 32; yy += 8) outp[(size_t)(n0 + y + yy) * 1024 + k0 + x] = f2bf(t[x][y + yy]);
  } else if (b < 4608){
    int base = (b - 4096) * 8192;
    #pragma unroll
    for (int j = 0; j < 8; j++){
      int i = base + j * 1024 + tid * 4;
      float4 f = *(const float4*)&hidden[i];
      uint2 p; p.x = packbf(f.x, f.y); p.y = packbf(f.z, f.w);
      *(uint2*)&hb[i] = p;
    }
  } else if (b == 4608){
    #pragma unroll
    for (int j = 0; j < 12; j++){
      int i = j * 256 + tid;
      const float* src = i < 1024 ? bq : (i < 2048 ? bk : bv);
      bcat[i] = src[i & 1023];
    }
  } else {
    int pb = b - 4609;   // [0,257)
    int d = tid & 63, part = tid >> 6;
    const float* W  = (pb < 256) ? Wk : Wq;
    const float* rv = (pb < 256) ? &rpe[(size_t)pb * 1024] : rpe;
    float s = 0.f;
    for (int k = part * 256; k < part * 256 + 256; k++) s += rv[k] * W[(size_t)k * 1024 + d];
    red[part][d] = s;
    __syncthreads();
    if (part == 0){
      s = red[0][d] + red[1][d] + red[2][d] + red[3][d];
      if (pb < 256) posk[pb * 64 + d] = s + bk[d];
      else          posq0[d] = s + bq[d];
    }
  }
}

// ---------------- QKV GEMM, 2-phase dbuf pipeline: qk[S][2048] = Q|K ; Vt[c][s] for V ----------------
__global__ __launch_bounds__(256) void k_gemm_qkv(const u16* __restrict__ A, const u16* __restrict__ Bt,
                                                  const float* __restrict__ bias,
                                                  u16* __restrict__ qk, u16* __restrict__ Vt)
{
  __shared__ alignas(16) u16 As[2][128 * 32];
  __shared__ alignas(16) u16 Bs[2][128 * 32];
  int tid = threadIdx.x, lane = tid & 63, wid = tid >> 6;
  int wr = wid >> 1, wc = wid & 1;
  int m0 = blockIdx.y * 128, n0 = blockIdx.x * 128;
  const int K = 1024;

  v4f acc[4][4];
  #pragma unroll
  for (int m = 0; m < 4; m++)
    #pragma unroll
    for (int n = 0; n < 4; n++) acc[m][n] = (v4f){0.f, 0.f, 0.f, 0.f};

  int r = lane & 15, g = lane >> 4;
  int ob0 = wid * 2048;
  int o0  = ob0 + lane * 16;
  int row0 = o0 >> 6, col0 = (o0 & 63) >> 1;
  int row1 = (o0 + 1024) >> 6, col1 = ((o0 + 1024) & 63) >> 1;

  GLOAD_LDS16(&A [(size_t)(m0 + row0) * K + col0], &As[0][ob0 >> 1]);
  GLOAD_LDS16(&Bt[(size_t)(n0 + row0) * K + col0], &Bs[0][ob0 >> 1]);
  GLOAD_LDS16(&A [(size_t)(m0 + row1) * K + col1], &As[0][(ob0 + 1024) >> 1]);
  GLOAD_LDS16(&Bt[(size_t)(n0 + row1) * K + col1], &Bs[0][(ob0 + 1024) >> 1]);
  __syncthreads();

  int cur = 0;
  for (int kt = 0; kt < K - 32; kt += 32){
    int nx = cur ^ 1, kn = kt + 32;
    GLOAD_LDS16(&A [(size_t)(m0 + row0) * K + kn + col0], &As[nx][ob0 >> 1]);
    GLOAD_LDS16(&Bt[(size_t)(n0 + row0) * K + kn + col0], &Bs[nx][ob0 >> 1]);
    GLOAD_LDS16(&A [(size_t)(m0 + row1) * K + kn + col1], &As[nx][(ob0 + 1024) >> 1]);
    GLOAD_LDS16(&Bt[(size_t)(n0 + row1) * K + kn + col1], &Bs[nx][(ob0 + 1024) >> 1]);

    v8bf a[4], bb[4];
    #pragma unroll
    for (int m = 0; m < 4; m++) a[m] = *(const v8bf*)&As[cur][(wr * 64 + m * 16 + r) * 32 + g * 8];
    #pragma unroll
    for (int n = 0; n < 4; n++) bb[n] = *(const v8bf*)&Bs[cur][(wc * 64 + n * 16 + r) * 32 + g * 8];
    #pragma unroll
    for (int m = 0; m < 4; m++)
      #pragma unroll
      for (int n = 0; n < 4; n++)
        acc[m][n] = __builtin_amdgcn_mfma_f32_16x16x32_bf16(a[m], bb[n], acc[m][n], 0, 0, 0);
    __syncthreads();
    cur = nx;
  }
  {
    v8bf a[4], bb[4];
    #pragma unroll
    for (int m = 0; m < 4; m++) a[m] = *(const v8bf*)&As[cur][(wr * 64 + m * 16 + r) * 32 + g * 8];
    #pragma unroll
    for (int n = 0; n < 4; n++) bb[n] = *(const v8bf*)&Bs[cur][(wc * 64 + n * 16 + r) * 32 + g * 8];
    #pragma unroll
    for (int m = 0; m < 4; m++)
      #pragma unroll
      for (int n = 0; n < 4; n++)
        acc[m][n] = __builtin_amdgcn_mfma_f32_16x16x32_bf16(a[m], bb[n], acc[m][n], 0, 0, 0);
  }

  #pragma unroll
  for (int m = 0; m < 4; m++)
    #pragma unroll
    for (int n = 0; n < 4; n++){
      int col = n0 + wc * 64 + n * 16 + r;
      float bv = bias[col];
      if (n0 < 2048){
        #pragma unroll
        for (int i = 0; i < 4; i++){
          int row = m0 + wr * 64 + m * 16 + g * 4 + i;
          qk[(size_t)row * 2048 + col] = f2bf(acc[m][n][i] + bv);
        }
      } else {
        uint2 pk;
        pk.x = packbf(acc[m][n][0] + bv, acc[m][n][1] + bv);
        pk.y = packbf(acc[m][n][2] + bv, acc[m][n][3] + bv);
        int row = m0 + wr * 64 + m * 16 + g * 4;
        *(uint2*)&Vt[(size_t)(col - 2048) * 4096 + row] = pk;
      }
    }
}

// ---------------- out GEMM + residual, same 2-phase dbuf ----------------
__global__ __launch_bounds__(256) void k_gemm_out(const u16* __restrict__ A, const u16* __restrict__ Bt,
                                                  const float* __restrict__ bias,
                                                  const float* __restrict__ resid, float* __restrict__ Cout)
{
  __shared__ alignas(16) u16 As[2][128 * 32];
  __shared__ alignas(16) u16 Bs[2][128 * 32];
  int tid = threadIdx.x, lane = tid & 63, wid = tid >> 6;
  int wr = wid >> 1, wc = wid & 1;
  int m0 = blockIdx.y * 128, n0 = blockIdx.x * 128;
  const int K = 1024;

  v4f acc[4][4];
  #pragma unroll
  for (int m = 0; m < 4; m++)
    #pragma unroll
    for (int n = 0; n < 4; n++) acc[m][n] = (v4f){0.f, 0.f, 0.f, 0.f};

  int r = lane & 15, g = lane >> 4;
  int ob0 = wid * 2048;
  int o0  = ob0 + lane * 16;
  int row0 = o0 >> 6, col0 = (o0 & 63) >> 1;
  int row1 = (o0 + 1024) >> 6, col1 = ((o0 + 1024) & 63) >> 1;

  GLOAD_LDS16(&A [(size_t)(m0 + row0) * K + col0], &As[0][ob0 >> 1]);
  GLOAD_LDS16(&Bt[(size_t)(n0 + row0) * K + col0], &Bs[0][ob0 >> 1]);
  GLOAD_LDS16(&A [(size_t)(m0 + row1) * K + col1], &As[0][(ob0 + 1024) >> 1]);
  GLOAD_LDS16(&Bt[(size_t)(n0 + row1) * K + col1], &Bs[0][(ob0 + 1024) >> 1]);
  __syncthreads();

  int cur = 0;
  for (int kt = 0; kt < K - 32; kt += 32){
    int nx = cur ^ 1, kn = kt + 32;
    GLOAD_LDS16(&A [(size_t)(m0 + row0) * K + kn + col0], &As[nx][ob0 >> 1]);
    GLOAD_LDS16(&Bt[(size_t)(n0 + row0) * K + kn + col0], &Bs[nx][ob0 >> 1]);
    GLOAD_LDS16(&A [(size_t)(m0 + row1) * K + kn + col1], &As[nx][(ob0 + 1024) >> 1]);
    GLOAD_LDS16(&Bt[(size_t)(n0 + row1) * K + kn + col1], &Bs[nx][(ob0 + 1024) >> 1]);

    v8bf a[4], bb[4];
    #pragma unroll
    for (int m = 0; m < 4; m++) a[m] = *(const v8bf*)&As[cur][(wr * 64 + m * 16 + r) * 32 + g * 8];
    #pragma unroll
    for (int n = 0; n < 4; n++) bb[n] = *(const v8bf*)&Bs[cur][(wc * 64 + n * 16 + r) * 32 + g * 8];
    #pragma unroll
    for (int m = 0; m < 4; m++)
      #pragma unroll
      for (int n = 0; n < 4; n++)
        acc[m][n] = __builtin_amdgcn_mfma_f32_16x16x32_bf16(a[m], bb[n], acc[m][n], 0, 0, 0);
    __syncthreads();
    cur = nx;
  }
  {
    v8bf a[4], bb[4];
    #pragma unroll
    for (int m = 0; m < 4; m++) a[m] = *(const v8bf*)&As[cur][(wr * 64 + m * 16 + r) * 32 + g * 8];
    #pragma unroll
    for (int n = 0; n < 4; n++) bb[n] = *(const v8bf*)&Bs[cur][(wc * 64 + n * 16 + r) * 32 + g * 8];
    #pragma unroll
    for (int m = 0; m < 4; m++)
      #pragma unroll
      for (int n = 0; n < 4; n++)
        acc[m][n] = __builtin_amdgcn_mfma_f32_16x16x32_bf16(a[m], bb[n], acc[m][n], 0, 0, 0);
  }

  #pragma unroll
  for (int m = 0; m < 4; m++)
    #pragma unroll
    for (int n = 0; n < 4; n++){
      int col = n0 + wc * 64 + n * 16 + r;
      float bv = bias[col];
      #pragma unroll
      for (int i = 0; i < 4; i++){
        int row = m0 + wr * 64 + m * 16 + g * 4 + i;
        Cout[(size_t)row * 1024 + col] = acc[m][n][i] + bv + resid[(size_t)row * 1024 + col];
      }
    }
}

// ---------------- brow: 8 WGs, 32 rows each; also zeros brow[0,256) ----------------
__global__ __launch_bounds__(256) void k_brow(const u16* __restrict__ qk,
                                              const float* __restrict__ posk, const float* __restrict__ posq0,
                                              float* __restrict__ brow)
{
  int b = blockIdx.x, tid = threadIdx.x;
  if (tid < 32) brow[b * 32 + tid] = 0.f;
  int u = b * 32 + (tid >> 3), sub = tid & 7;
  float c2p = 0.f, p2c = 0.f;
  #pragma unroll
  for (int j = 0; j < 8; j++){
    int d = sub * 8 + j;
    c2p += bf2f(qk[d]) * posk[u * 64 + d];
    p2c += posq0[d] * bf2f(qk[(size_t)u * 2048 + 1024 + d]);
  }
  float v = c2p + p2c;
  v += __shfl_xor(v, 1);
  v += __shfl_xor(v, 2);
  v += __shfl_xor(v, 4);
  if (sub == 0) brow[256 + u] = v;
}

// ---------------- biasd[t] = brow[clip(bucket(t-767)+256)] * c1 (prescaled) ----------------
__global__ void k_biasd(const float* __restrict__ brow, float* __restrict__ biasd)
{
  const float c1 = 0.07216878364870323f * 1.4426950408889634f;  // 1/sqrt(192)*log2e
  int t = blockIdx.x * blockDim.x + threadIdx.x;   // 1024
  int rel = t - 767;
  int bucket;
  bool in_exact = (rel < 128) && (rel > -128);
  int abs_pos = in_exact ? 127 : (rel < 0 ? -rel : rel);
  if (abs_pos <= 128) bucket = rel;
  else {
    float xx = logf((float)abs_pos * (1.0f / 128.0f)) / logf(255.0f / 128.0f);
    float lp = ceilf(xx * 127.0f) + 128.0f;
    int sgn = (rel > 0) ? 1 : ((rel < 0) ? -1 : 0);
    bucket = (int)lp * sgn;
  }
  int idx = bucket + 256;
  idx = idx < 0 ? 0 : (idx > 511 ? 511 : idx);
  biasd[t] = brow[idx] * c1;
}

// ---------------- flash attention, swapped QK^T, in-register P (tile-major grid) ----------------
__global__ __launch_bounds__(256) void k_attn(const u16* __restrict__ qk, const u16* __restrict__ Vt,
                                              const float* __restrict__ biasd, u16* __restrict__ ctxg)
{
  __shared__ alignas(16) u16 Ks[128 * 64];     // 16KB, slot-swizzled rows
  __shared__ alignas(16) u16 Vs[64 * 128];     // 16KB, slot-swizzled rows (d-major)
  __shared__ float bias_s[1024];               // prescaled by c1

  int b = blockIdx.x;
  int h = b & 15, tile = b >> 4;               // tile-major: 16 heads of same tile adjacent
  int n = tile >> 2, qb0 = (tile & 3) * 64;
  int tid = threadIdx.x, lane = tid & 63, w = tid >> 6;
  int q0 = tile * 64;
  int g0 = (n - 1) * 256;
  const float c1 = 0.07216878364870323f * 1.4426950408889634f;  // 1/sqrt(192)*log2e
  int r = lane & 15, g = lane >> 4;

  *(float4*)&bias_s[tid * 4] = *(const float4*)&biasd[tid * 4];

  // Q fragments (B-operand): lane holds Q[q0+w*16+r][ks*32 + g*8 + j]
  v8bf qfrag[2];
  {
    const u16* src = &qk[(size_t)(q0 + w * 16 + r) * 2048 + h * 64 + g * 8];
    qfrag[0] = *(const v8bf*)&src[0];
    qfrag[1] = *(const v8bf*)&src[32];
  }

  float mrun = -3.0e38f, lrun = 0.f;
  v4f pacc[4];                                  // O[q=g*4+i][d=nn*16+r]
  #pragma unroll
  for (int nn = 0; nn < 4; nn++) pacc[nn] = (v4f){0.f,0.f,0.f,0.f};

  int idxA = r + ((g & 1) << 5);                // exchange sources
  int idxB = idxA + 16;
  int myrnd = g >> 1;

  for (int c = 0; c < 6; ++c){
    int cb = g0 + c * 128;
    bool oob = (cb < 0) || (cb >= SEQ);
    if (!oob){
      #pragma unroll
      for (int t = 0; t < 4; ++t){       // K rows w*32 + t*8 + (lane>>3)
        int row = w * 32 + t * 8 + (lane >> 3);
        int p = lane & 7;
        GLOAD_LDS16(&qk[(size_t)(cb + row) * 2048 + 1024 + h * 64 + ((p ^ (row & 7)) * 8)],
                    Ks + (size_t)(w * 32 + t * 8) * 64);
      }
      #pragma unroll
      for (int t = 0; t < 4; ++t){       // V d-rows w*16 + t*4 + (lane>>4)
        int d = w * 16 + t * 4 + (lane >> 4);
        int p = lane & 15;
        GLOAD_LDS16(&Vt[(size_t)(h * 64 + d) * 4096 + cb + ((p ^ (d & 7)) * 8)],
                    Vs + (size_t)(w * 16 + t * 4) * 128);
      }
    }
    __syncthreads();

    // swapped QK: sacc[t] = P fragment, rows k = t*16 + g*4 + i, col q = r
    v4f sacc[8];
    #pragma unroll
    for (int t = 0; t < 8; t++) sacc[t] = (v4f){0.f,0.f,0.f,0.f};
    if (!oob){
      __builtin_amdgcn_s_setprio(1);
      #pragma unroll
      for (int ks = 0; ks < 2; ++ks){
        #pragma unroll
        for (int t = 0; t < 8; t++){
          int kr = t * 16 + r;
          v8bf kf = *(const v8bf*)&Ks[kr * 64 + (((4 * ks + g) ^ (kr & 7)) * 8)];
          sacc[t] = __builtin_amdgcn_mfma_f32_16x16x32_bf16(kf, qfrag[ks], sacc[t], 0, 0, 0);
        }
      }
      __builtin_amdgcn_s_setprio(0);
    }

    // scores (prescaled bias -> single fma) + in-lane chunk max
    float sv[8][4];
    float cmax = -3.0e38f;
    int ib = qb0 + w * 16 + r + 767 - c * 128 - g * 4;
    #pragma unroll
    for (int t = 0; t < 8; t++){
      #pragma unroll
      for (int i = 0; i < 4; i++)
        sv[t][i] = fmaf(sacc[t][i], c1, bias_s[ib - t * 16 - i]);
      float m01 = fmaxf(sv[t][0], sv[t][1]);
      float m23 = fmaxf(sv[t][2], sv[t][3]);
      cmax = fmaxf(cmax, fmaxf(m01, m23));
    }
    cmax = fmaxf(cmax, __shfl_xor(cmax, 16));
    cmax = fmaxf(cmax, __shfl_xor(cmax, 32));
    // defer-max: only rescale when the chunk max meaningfully exceeds the running max
    if (!__all(cmax <= mrun + 8.f)){
      float mn = fmaxf(mrun, cmax);
      float sc = exp2f(mrun - mn);
      mrun = mn;
      lrun *= sc;
      #pragma unroll
      for (int i = 0; i < 4; i++){
        float sci = __shfl(sc, (g << 2) + i);
        #pragma unroll
        for (int nn = 0; nn < 4; nn++) pacc[nn][i] *= sci;
      }
    }

    // exp + bf16 pack via v_cvt_pk_bf16_f32
    unsigned pk0[8], pk1[8];
    #pragma unroll
    for (int t = 0; t < 8; t++){
      float p0 = exp2f(sv[t][0] - mrun);
      float p1 = exp2f(sv[t][1] - mrun);
      float p2 = exp2f(sv[t][2] - mrun);
      float p3 = exp2f(sv[t][3] - mrun);
      lrun += (p0 + p1) + (p2 + p3);
      pk0[t] = packbf(p0, p1);
      pk1[t] = packbf(p2, p3);
    }

    // exchange + PV: A-frag for ks block bb4 = P[q=r][k = bb4*32 + g*8 + j]
    if (!oob){
      #pragma unroll
      for (int bb4 = 0; bb4 < 4; ++bb4){
        unsigned s0a = 0, s1a = 0, s0b = 0, s1b = 0;
        #pragma unroll
        for (int rnd = 0; rnd < 2; ++rnd){
          int t = 2 * bb4 + rnd;
          unsigned ta0 = __shfl(pk0[t], idxA);
          unsigned ta1 = __shfl(pk1[t], idxA);
          unsigned tb0 = __shfl(pk0[t], idxB);
          unsigned tb1 = __shfl(pk1[t], idxB);
          if (myrnd == rnd){ s0a = ta0; s1a = ta1; s0b = tb0; s1b = tb1; }
        }
        union { unsigned u[4]; v8bf v; } af;
        af.u[0] = s0a; af.u[1] = s1a; af.u[2] = s0b; af.u[3] = s1b;
        __builtin_amdgcn_s_setprio(1);
        #pragma unroll
        for (int nn = 0; nn < 4; nn++){
          int d = nn * 16 + r;
          v8bf vb = *(const v8bf*)&Vs[d * 128 + (((4 * bb4 + g) ^ (d & 7)) * 8)];
          pacc[nn] = __builtin_amdgcn_mfma_f32_16x16x32_bf16(af.v, vb, pacc[nn], 0, 0, 0);
        }
        __builtin_amdgcn_s_setprio(0);
      }
    }
    __syncthreads();   // protect Ks/Vs for next chunk
  }

  // final: l for q=r across g-groups, broadcast inverse to output-row owners
  lrun += __shfl_xor(lrun, 16);
  lrun += __shfl_xor(lrun, 32);
  float inv = 1.0f / lrun;
  #pragma unroll
  for (int nn = 0; nn < 4; nn++){
    int d = nn * 16 + r;
    #pragma unroll
    for (int i = 0; i < 4; i++){
      float invi = __shfl(inv, (g << 2) + i);
      int qrow = q0 + w * 16 + g * 4 + i;
      ctxg[(size_t)qrow * 1024 + h * 64 + d] = f2bf(pacc[nn][i] * invi);
    }
  }
}

// ---------------- LayerNorm in place (residual already folded into out) ----------------
__global__ __launch_bounds__(256) void k_ln(float* __restrict__ out,
                                            const float* __restrict__ gamma, const float* __restrict__ beta)
{
  __shared__ float red[8];
  int row = blockIdx.x, tid = threadIdx.x;
  int lane = tid & 63, wid = tid >> 6;
  size_t base = (size_t)row * 1024 + tid * 4;
  float4 xv = *(const float4*)&out[base];
  float v0 = xv.x, v1 = xv.y, v2 = xv.z, v3 = xv.w;
  float s = v0 + v1 + v2 + v3;
  float q = v0 * v0 + v1 * v1 + v2 * v2 + v3 * v3;
  #pragma unroll
  for (int o = 32; o; o >>= 1){ s += __shfl_down(s, o); q += __shfl_down(q, o); }
  if (lane == 0){ red[wid] = s; red[4 + wid] = q; }
  __syncthreads();
  float ts = red[0] + red[1] + red[2] + red[3];
  float tq = red[4] + red[5] + red[6] + red[7];
  float mu = ts * (1.0f / 1024.0f);
  float var = tq * (1.0f / 1024.0f) - mu * mu;
  float rstd = rsqrtf(var + 1e-7f);
  int c = tid * 4;
  out[base + 0] = (v0 - mu) * rstd * gamma[c + 0] + beta[c + 0];
  out[base + 1] = (v1 - mu) * rstd * gamma[c + 1] + beta[c + 1];
  out[base + 2] = (v2 - mu) * rstd * gamma[c + 2] + beta[c + 2];
  out[base + 3] = (v3 - mu) * rstd * gamma[c + 3] + beta[c + 3];
}

extern "C" void kernel_launch(void* const* d_in, const int* in_sizes, int n_in,
                              void* d_out, int out_size, void* d_ws, size_t ws_size,
                              hipStream_t stream)
{
  const float* hidden = (const float*)d_in[0];
  const float* rpe    = (const float*)d_in[1];
  const float* Wq = (const float*)d_in[2];
  const float* bq = (const float*)d_in[3];
  const float* Wk = (const float*)d_in[4];
  const float* bk = (const float*)d_in[5];
  const float* Wv = (const float*)d_in[6];
  const float* bv = (const float*)d_in[7];
  const float* Wo = (const float*)d_in[8];
  const float* bo = (const float*)d_in[9];
  const float* lns = (const float*)d_in[10];
  const float* lnb = (const float*)d_in[11];
  float* out = (float*)d_out;

  char* ws = (char*)d_ws;
  size_t off = 0;
  auto alloc = [&](size_t bytes){ void* p = ws + off; off += (bytes + 255) & ~(size_t)255; return p; };
  u16* hb      = (u16*)alloc((size_t)SEQ * HIDN * 2);
  u16* Wt      = (u16*)alloc((size_t)4 * HIDN * HIDN * 2);    // [Wqt|Wkt|Wvt|Wot]
  u16* qk      = (u16*)alloc((size_t)SEQ * 2048 * 2);
  u16* Vt      = (u16*)alloc((size_t)HIDN * SEQ * 2);
  u16* ctxb    = (u16*)alloc((size_t)SEQ * HIDN * 2);
  float* bcat  = (float*)alloc(3072 * 4);
  float* poskf = (float*)alloc(256 * 64 * 4);
  float* posq0 = (float*)alloc(64 * 4);
  float* brow  = (float*)alloc(512 * 4);
  float* biasd = (float*)alloc(1024 * 4);
  (void)ws_size; (void)in_sizes; (void)n_in; (void)out_size;

  k_prep<<<4866, 256, 0, stream>>>(hidden, hb, Wq, Wk, Wv, Wo, Wt,
                                   bq, bk, bv, bcat, rpe, poskf, posq0);

  k_gemm_qkv<<<dim3(24, 32), 256, 0, stream>>>(hb, Wt, bcat, qk, Vt);

  k_brow<<<8, 256, 0, stream>>>(qk, poskf, posq0, brow);
  k_biasd<<<4, 256, 0, stream>>>(brow, biasd);

  k_attn<<<64 * NHEAD, 256, 0, stream>>>(qk, Vt, biasd, ctxb);

  k_gemm_out<<<dim3(8, 32), 256, 0, stream>>>(ctxb, Wt + (size_t)3 * HIDN * HIDN, bo, hidden, out);

  k_ln<<<SEQ, 256, 0, stream>>>(out, lns, lnb);
}